// Round 5
// baseline (808.507 us; speedup 1.0000x reference)
//
#include <hip/hip_runtime.h>
#include <cstddef>

// Multigrid F-cycle advection, 4096^2 f32, T=4 outer iterations.
// R4 (resubmit; prior round hit GPUAcquisitionTimeout — never benched):
// fine-grid stays as R2's lean streaming kernels (SR, k_final);
// the ENTIRE pyramid (r2..r5 restrict chain, coarse V-bottom,
// E5..E1 up-sweep) is ONE persistent 128-block kernel with 4
// device-scope grid barriers. Per iteration: 3 launches.
// All FP op orders identical to R2 (passing, absmax 3.814697e-06).

constexpr float CW = 0.05f;  // CXW == CYW == DT/DX/2
#define NBLK 128u

// e_new = (Pc - smooth_zero_pad(P)) + r, reference rounding order.
__device__ __forceinline__ float up_val(float Pc, float Pu, float Pd, float Pl,
                                        float Pr, float rv) {
  float sm = CW * Pu - CW * Pd + CW * Pl + Pc - CW * Pr;
  return (Pc - sm) + rv;
}

// Device-scope grid barrier: one-shot counter per barrier (zeroed by k_zero).
__device__ __forceinline__ void grid_barrier(unsigned int* cnt, unsigned int target) {
  __syncthreads();
  __threadfence();  // release: make this block's global writes visible (agent scope)
  if (threadIdx.x == 0) {
    __hip_atomic_fetch_add(cnt, 1u, __ATOMIC_ACQ_REL, __HIP_MEMORY_SCOPE_AGENT);
    while (__hip_atomic_load(cnt, __ATOMIC_RELAXED, __HIP_MEMORY_SCOPE_AGENT) < target) {
      __builtin_amdgcn_s_sleep(1);
    }
  }
  __syncthreads();
  __threadfence();  // acquire side for all threads
}

__global__ void k_zero(unsigned int* p, int n) {
  int i = blockIdx.x * blockDim.x + threadIdx.x;
  if (i < n) p[i] = 0u;
}

// ---------------------------------------------------------------------------
// r1 = restrict(smooth(bc(v))): v 4096^2 -> r1 2048^2.  (verbatim R2)
__global__ __launch_bounds__(256) void k_smooth_restrict(
    const float* __restrict__ v, float* __restrict__ r1) {
  const int n = 4096, h = 2048;
  int bj = blockIdx.x * blockDim.x + threadIdx.x;
  int bi = blockIdx.y * blockDim.y + threadIdx.y;
  int c0 = 4 * bj;
  int cl = max(c0 - 1, 0), cr = min(c0 + 4, n - 1);
  float a[6][6];
#pragma unroll
  for (int rr = 0; rr < 6; ++rr) {
    int R = min(max(4 * bi - 1 + rr, 0), n - 1);
    const float* row = v + (size_t)R * n;
    float4 m = *reinterpret_cast<const float4*>(row + c0);
    a[rr][0] = row[cl];
    a[rr][1] = m.x; a[rr][2] = m.y; a[rr][3] = m.z; a[rr][4] = m.w;
    a[rr][5] = row[cr];
  }
#pragma unroll
  for (int oi = 0; oi < 2; ++oi) {
    float2 o;
#pragma unroll
    for (int oj = 0; oj < 2; ++oj) {
      float s[2][2];
#pragma unroll
      for (int p = 0; p < 2; ++p)
#pragma unroll
        for (int q = 0; q < 2; ++q) {
          int P = 2 * oi + p, Q = 2 * oj + q;
          s[p][q] = CW * a[P][Q + 1] - CW * a[P + 2][Q + 1]
                  + CW * a[P + 1][Q] + a[P + 1][Q + 1] - CW * a[P + 1][Q + 2];
        }
      float val = 0.25f * (((s[0][0] + s[1][0]) + s[0][1]) + s[1][1]);
      (oj ? o.y : o.x) = val;
    }
    *reinterpret_cast<float2*>(r1 + (size_t)(2 * bi + oi) * h + 2 * bj) = o;
  }
}

// ---------------------------------------------------------------------------
// One 2x4 up-tile (verbatim k_up body from R2).
__device__ __forceinline__ void up_tile24(const float* __restrict__ Ep,
                                          const float* __restrict__ r,
                                          float* __restrict__ Eo,
                                          int n, int i, int j) {
  int s = n >> 1;
  const float* ec = Ep + (size_t)i * s + 2 * j;
  float epc0 = ec[0], epc1 = ec[1];
  float epl = (j > 0) ? ec[-1] : 0.0f;
  float epr = (2 * j + 2 < s) ? ec[2] : 0.0f;
  float epu0 = 0.0f, epu1 = 0.0f, epd0 = 0.0f, epd1 = 0.0f;
  if (i > 0)     { epu0 = ec[-s]; epu1 = ec[-s + 1]; }
  if (i < s - 1) { epd0 = ec[s];  epd1 = ec[s + 1]; }
  {
    float4 rv = *reinterpret_cast<const float4*>(r + (size_t)(2 * i) * n + 4 * j);
    float4 o;
    o.x = up_val(epc0, epu0, epc0, epl,  epc0, rv.x);
    o.y = up_val(epc0, epu0, epc0, epc0, epc1, rv.y);
    o.z = up_val(epc1, epu1, epc1, epc0, epc1, rv.z);
    o.w = up_val(epc1, epu1, epc1, epc1, epr,  rv.w);
    *reinterpret_cast<float4*>(Eo + (size_t)(2 * i) * n + 4 * j) = o;
  }
  {
    float4 rv = *reinterpret_cast<const float4*>(r + (size_t)(2 * i + 1) * n + 4 * j);
    float4 o;
    o.x = up_val(epc0, epc0, epd0, epl,  epc0, rv.x);
    o.y = up_val(epc0, epc0, epd0, epc0, epc1, rv.y);
    o.z = up_val(epc1, epc1, epd1, epc0, epc1, rv.z);
    o.w = up_val(epc1, epc1, epd1, epc1, epr,  rv.w);
    *reinterpret_cast<float4*>(Eo + (size_t)(2 * i + 1) * n + 4 * j) = o;
  }
}

// ---------------------------------------------------------------------------
// Persistent pyramid kernel: r1 -> {r2,r3,r4,r5} -> coarse V-bottom (LDS,
// redundant per block) -> E4 -> E3 -> E2 -> E1. 4 grid barriers.
__global__ __launch_bounds__(256, 1) void k_pyramid(
    const float* __restrict__ r1, float* __restrict__ r2,
    float* __restrict__ r3, float* __restrict__ r4, float* __restrict__ r5,
    float* __restrict__ E4, float* __restrict__ E3, float* __restrict__ E2,
    float* __restrict__ E1, unsigned int* __restrict__ bars) {
  __shared__ float r5s[128 * 128];
  __shared__ float r6s[64 * 64];
  __shared__ float r7s[32 * 32];
  __shared__ float r8s[16 * 16];
  __shared__ float r9s[8 * 8];
  __shared__ float E8s[16 * 16];
  __shared__ float E7s[32 * 32];
  __shared__ float E6s[64 * 64];
  __shared__ float e5r[3][128];
  int tid = threadIdx.x;
  int bid = blockIdx.x;
  int g = bid * 256 + tid;

  // ---- Phase 1: thread-local restrict chain r1 -> r2,r3,r4,r5 -------------
  if (g < 16384) {
    int i5 = g >> 7, j5 = g & 127;
    const float* src = r1 + (size_t)(i5 << 4) * 2048 + (j5 << 4);
    float rr2[8][8];
#pragma unroll
    for (int a = 0; a < 8; ++a) {
      float ta[16], tb[16];
      const float* ra = src + (size_t)(2 * a) * 2048;
      const float* rb = ra + 2048;
#pragma unroll
      for (int q = 0; q < 4; ++q) {
        *reinterpret_cast<float4*>(ta + 4 * q) = reinterpret_cast<const float4*>(ra)[q];
        *reinterpret_cast<float4*>(tb + 4 * q) = reinterpret_cast<const float4*>(rb)[q];
      }
#pragma unroll
      for (int b = 0; b < 8; ++b)
        rr2[a][b] = 0.25f * (((ta[2 * b] + tb[2 * b]) + ta[2 * b + 1]) + tb[2 * b + 1]);
      float* dst = r2 + (size_t)((i5 << 3) + a) * 1024 + (j5 << 3);
      float4 o0, o1;
      o0.x = rr2[a][0]; o0.y = rr2[a][1]; o0.z = rr2[a][2]; o0.w = rr2[a][3];
      o1.x = rr2[a][4]; o1.y = rr2[a][5]; o1.z = rr2[a][6]; o1.w = rr2[a][7];
      reinterpret_cast<float4*>(dst)[0] = o0;
      reinterpret_cast<float4*>(dst)[1] = o1;
    }
    float rr3[4][4];
#pragma unroll
    for (int a = 0; a < 4; ++a) {
#pragma unroll
      for (int b = 0; b < 4; ++b)
        rr3[a][b] = 0.25f * (((rr2[2 * a][2 * b] + rr2[2 * a + 1][2 * b])
                              + rr2[2 * a][2 * b + 1]) + rr2[2 * a + 1][2 * b + 1]);
      float4 o;
      o.x = rr3[a][0]; o.y = rr3[a][1]; o.z = rr3[a][2]; o.w = rr3[a][3];
      *reinterpret_cast<float4*>(r3 + (size_t)((i5 << 2) + a) * 512 + (j5 << 2)) = o;
    }
    float rr4[2][2];
#pragma unroll
    for (int a = 0; a < 2; ++a) {
#pragma unroll
      for (int b = 0; b < 2; ++b)
        rr4[a][b] = 0.25f * (((rr3[2 * a][2 * b] + rr3[2 * a + 1][2 * b])
                              + rr3[2 * a][2 * b + 1]) + rr3[2 * a + 1][2 * b + 1]);
      float2 o;
      o.x = rr4[a][0]; o.y = rr4[a][1];
      *reinterpret_cast<float2*>(r4 + (size_t)((i5 << 1) + a) * 256 + (j5 << 1)) = o;
    }
    r5[(size_t)i5 * 128 + j5] =
        0.25f * (((rr4[0][0] + rr4[1][0]) + rr4[0][1]) + rr4[1][1]);
  }
  grid_barrier(bars + 0, NBLK);

  // ---- Phase 2: per-block coarse V-bottom in LDS; write 2 rows of E4 ------
  {
    auto up_lds = [&](const float* Ep, const float* rr, int i, int c, int nn) {
      int ss = nn >> 1;
      float Pc = Ep[(i >> 1) * ss + (c >> 1)];
      float Pu = (i > 0)      ? Ep[((i - 1) >> 1) * ss + (c >> 1)] : 0.0f;
      float Pd = (i < nn - 1) ? Ep[((i + 1) >> 1) * ss + (c >> 1)] : 0.0f;
      float Pl = (c > 0)      ? Ep[(i >> 1) * ss + ((c - 1) >> 1)] : 0.0f;
      float Pr = (c < nn - 1) ? Ep[(i >> 1) * ss + ((c + 1) >> 1)] : 0.0f;
      return up_val(Pc, Pu, Pd, Pl, Pr, rr[i * nn + c]);
    };
    for (int idx = tid; idx < 4096; idx += 256)
      reinterpret_cast<float4*>(r5s)[idx] = reinterpret_cast<const float4*>(r5)[idx];
    __syncthreads();
    for (int idx = tid; idx < 64 * 64; idx += 256) {
      int I = idx >> 6, J = idx & 63;
      float a = r5s[(2 * I) * 128 + 2 * J],     b = r5s[(2 * I + 1) * 128 + 2 * J];
      float c = r5s[(2 * I) * 128 + 2 * J + 1], d = r5s[(2 * I + 1) * 128 + 2 * J + 1];
      r6s[idx] = 0.25f * (((a + b) + c) + d);
    }
    __syncthreads();
    for (int idx = tid; idx < 32 * 32; idx += 256) {
      int I = idx >> 5, J = idx & 31;
      float a = r6s[(2 * I) * 64 + 2 * J],     b = r6s[(2 * I + 1) * 64 + 2 * J];
      float c = r6s[(2 * I) * 64 + 2 * J + 1], d = r6s[(2 * I + 1) * 64 + 2 * J + 1];
      r7s[idx] = 0.25f * (((a + b) + c) + d);
    }
    __syncthreads();
    for (int idx = tid; idx < 16 * 16; idx += 256) {
      int I = idx >> 4, J = idx & 15;
      float a = r7s[(2 * I) * 32 + 2 * J],     b = r7s[(2 * I + 1) * 32 + 2 * J];
      float c = r7s[(2 * I) * 32 + 2 * J + 1], d = r7s[(2 * I + 1) * 32 + 2 * J + 1];
      r8s[idx] = 0.25f * (((a + b) + c) + d);
    }
    __syncthreads();
    for (int idx = tid; idx < 8 * 8; idx += 256) {
      int I = idx >> 3, J = idx & 7;
      float a = r8s[(2 * I) * 16 + 2 * J],     b = r8s[(2 * I + 1) * 16 + 2 * J];
      float c = r8s[(2 * I) * 16 + 2 * J + 1], d = r8s[(2 * I + 1) * 16 + 2 * J + 1];
      r9s[idx] = 0.25f * (((a + b) + c) + d);
    }
    __syncthreads();
    for (int idx = tid; idx < 16 * 16; idx += 256)
      E8s[idx] = up_lds(r9s, r8s, idx >> 4, idx & 15, 16);
    __syncthreads();
    for (int idx = tid; idx < 32 * 32; idx += 256)
      E7s[idx] = up_lds(E8s, r7s, idx >> 5, idx & 31, 32);
    __syncthreads();
    for (int idx = tid; idx < 64 * 64; idx += 256)
      E6s[idx] = up_lds(E7s, r6s, idx >> 6, idx & 63, 64);
    __syncthreads();
    // E5 rows bid-1..bid+1 (clamped; OOB rows are never read thanks to guards)
    for (int idx = tid; idx < 3 * 128; idx += 256) {
      int rr = idx >> 7, c = idx & 127;
      int i = min(max(bid - 1 + rr, 0), 127);
      e5r[rr][c] = up_lds(E6s, r5s, i, c, 128);
    }
    __syncthreads();
    // E4 rows 2*bid, 2*bid+1 (n=256, s=128)
    for (int idx = tid; idx < 512; idx += 256) {
      int gi = 2 * bid + (idx >> 8);
      int gc = idx & 255;
      float Pc = e5r[1][gc >> 1];
      float Pu = (gi > 0)   ? e5r[((gi - 1) >> 1) - bid + 1][gc >> 1] : 0.0f;
      float Pd = (gi < 255) ? e5r[((gi + 1) >> 1) - bid + 1][gc >> 1] : 0.0f;
      float Pl = (gc > 0)   ? e5r[1][(gc - 1) >> 1] : 0.0f;
      float Pr = (gc < 255) ? e5r[1][(gc + 1) >> 1] : 0.0f;
      E4[(size_t)gi * 256 + gc] = up_val(Pc, Pu, Pd, Pl, Pr, r4[(size_t)gi * 256 + gc]);
    }
  }
  grid_barrier(bars + 1, NBLK);

  // ---- Phase 3: E3 = up(E4, r3), n=512: 32768 tiles, 1/thread -------------
  {
    int i = g >> 7, j = g & 127;
    up_tile24(E4, r3, E3, 512, i, j);
  }
  grid_barrier(bars + 2, NBLK);

  // ---- Phase 4: E2 = up(E3, r2), n=1024: 131072 tiles, 4/thread -----------
#pragma unroll
  for (int t = 0; t < 4; ++t) {
    int tile = g + t * 32768;
    up_tile24(E3, r2, E2, 1024, tile >> 8, tile & 255);
  }
  grid_barrier(bars + 3, NBLK);

  // ---- Phase 5: E1 = up(E2, r1), n=2048: 524288 tiles, 16/thread ----------
#pragma unroll
  for (int t = 0; t < 16; ++t) {
    int tile = g + t * 32768;
    up_tile24(E2, r1, E1, 2048, tile >> 9, tile & 511);
  }
}

// ---------------------------------------------------------------------------
// out = w - smooth(bc(w)), w = v - prolong(E1).  (verbatim R2)
__global__ __launch_bounds__(256) void k_final(
    const float* __restrict__ v, const float* __restrict__ E1,
    float* __restrict__ out) {
  const int n = 4096, h = 2048;
  int J = blockIdx.x * blockDim.x + threadIdx.x;
  int i = blockIdx.y * blockDim.y + threadIdx.y;
  int c0 = 4 * J;
  int cl = max(c0 - 1, 0), cr = min(c0 + 4, n - 1);
  int ecl = cl >> 1, ecr = cr >> 1;

  float e[3][4];
  int ers0 = max(2 * i - 1, 0) >> 1;
  int ers2 = min(2 * i + 2, n - 1) >> 1;
  const int ers[3] = {ers0, i, ers2};
#pragma unroll
  for (int t = 0; t < 3; ++t) {
    const float* erow = E1 + (size_t)ers[t] * h;
    e[t][0] = erow[ecl];
    e[t][1] = erow[2 * J];
    e[t][2] = erow[2 * J + 1];
    e[t][3] = erow[ecr];
  }

  float w[4][6];
  const int tmap[4] = {0, 1, 1, 2};
#pragma unroll
  for (int rr = 0; rr < 4; ++rr) {
    int R = min(max(2 * i - 1 + rr, 0), n - 1);
    int t = tmap[rr];
    const float* vrow = v + (size_t)R * n;
    float4 m = *reinterpret_cast<const float4*>(vrow + c0);
    w[rr][0] = vrow[cl] - e[t][0];
    w[rr][1] = m.x - e[t][1];
    w[rr][2] = m.y - e[t][1];
    w[rr][3] = m.z - e[t][2];
    w[rr][4] = m.w - e[t][2];
    w[rr][5] = vrow[cr] - e[t][3];
  }
#pragma unroll
  for (int a = 0; a < 2; ++a) {
    float4 o;
#pragma unroll
    for (int qq = 0; qq < 4; ++qq) {
      float ce = w[a + 1][qq + 1];
      float sm = CW * w[a][qq + 1] - CW * w[a + 2][qq + 1]
               + CW * w[a + 1][qq] + ce - CW * w[a + 1][qq + 2];
      (&o.x)[qq] = ce - sm;
    }
    *reinterpret_cast<float4*>(out + (size_t)(2 * i + a) * n + c0) = o;
  }
}

// ---------------------------------------------------------------------------
extern "C" void kernel_launch(void* const* d_in, const int* in_sizes, int n_in,
                              void* d_out, int out_size, void* d_ws, size_t ws_size,
                              hipStream_t stream) {
  (void)in_sizes; (void)n_in; (void)out_size;
  float* u = (float*)d_in[0];
  float* out = (float*)d_out;
  char* ws = (char*)d_ws;

  size_t off = 0;
  auto alloc = [&](size_t elems) {
    float* p = (float*)(ws + off);
    off += (elems * sizeof(float) + 255) & ~(size_t)255;
    return p;
  };
  float* r1 = alloc(2048 * 2048);
  float* r2 = alloc(1024 * 1024);
  float* r3 = alloc(512 * 512);
  float* r4 = alloc(256 * 256);
  float* r5 = alloc(128 * 128);
  float* E4 = alloc(256 * 256);
  float* E3 = alloc(512 * 512);
  float* E2 = alloc(1024 * 1024);
  float* E1 = alloc(2048 * 2048);
  unsigned int* bars = (unsigned int*)alloc(64);  // 16 counters (one-shot)
  size_t pool = off;
  const size_t VB = (size_t)4096 * 4096 * sizeof(float);
  bool big = ws_size >= pool + VB;
  float* vws = (float*)(ws + pool);

  dim3 b(64, 4);
  auto iterate = [&](const float* vin, float* vout, int it) {
    k_smooth_restrict<<<dim3(16, 256), b, 0, stream>>>(vin, r1);
    k_pyramid<<<NBLK, 256, 0, stream>>>(r1, r2, r3, r4, r5, E4, E3, E2, E1,
                                        bars + 4 * it);
    k_final<<<dim3(16, 512), b, 0, stream>>>(vin, E1, vout);
  };

  k_zero<<<1, 64, 0, stream>>>(bars, 16);
  if (big) {
    iterate(u, vws, 0);
    iterate(vws, out, 1);
    iterate(out, vws, 2);
    iterate(vws, out, 3);
  } else {
    iterate(u, out, 0);
    iterate(out, u, 1);
    iterate(u, out, 2);
    iterate(out, u, 3);
    hipMemcpyAsync(out, u, VB, hipMemcpyDeviceToDevice, stream);
  }
}

// Round 6
// 380.350 us; speedup vs baseline: 2.1257x; 2.1257x over previous
//
#include <hip/hip_runtime.h>
#include <cstddef>

// Multigrid F-cycle advection, 4096^2 f32, T=4 outer iterations.
// R6: back to R2's full-grid streaming structure, consolidated WITHOUT
// grid barriers (R5 post-mortem: persistent kernel = 6% chip utilization).
// Per iteration, 5 launches:
//   1. k_sr_chain : r1 = restrict(smooth(bc(v))) + in-LDS r2,r3,r4,r5
//   2. k_coarse_ext: per-block redundant r5->E6 LDS chain, writes E4
//   3. k_up_e3e2  : E3 in LDS (never global), writes E2
//   4. k_up(2048) : E1 = up(E2, r1)          (streaming)
//   5. k_final    : v' = w - smooth(bc(w)), w = v - prolong(E1)
// All FP op orders identical to R2 (passing, absmax 3.814697e-06).

constexpr float CW = 0.05f;  // CXW == CYW == DT/DX/2

// e_new = (Pc - smooth_zero_pad(P)) + r, reference rounding order.
__device__ __forceinline__ float up_val(float Pc, float Pu, float Pd, float Pl,
                                        float Pr, float rv) {
  float sm = CW * Pu - CW * Pd + CW * Pl + Pc - CW * Pr;
  return (Pc - sm) + rv;
}

// ---------------------------------------------------------------------------
// k_sr_chain: block computes 64x64 r1 tile (R2 SR per-unit code), then
// in-LDS restricts to r2 (32x32), r3 (16x16), r4 (8x8), r5 (4x4).
__global__ __launch_bounds__(256) void k_sr_chain(
    const float* __restrict__ v, float* __restrict__ r1,
    float* __restrict__ r2, float* __restrict__ r3,
    float* __restrict__ r4, float* __restrict__ r5) {
  const int n = 4096, h = 2048;
  __shared__ float r1s[64][65];
  __shared__ float r2s[32][33];
  __shared__ float r3s[16][17];
  __shared__ float r4s[8][9];
  int tid = threadIdx.x;
  int bx = blockIdx.x, by = blockIdx.y;
  int ty0 = by * 64, tx0 = bx * 64;  // r1 tile origin

  // Phase A: 32x32 units of 2x2 r1; 4 units/thread. Verbatim R2 SR math.
#pragma unroll
  for (int k = 0; k < 4; ++k) {
    int u = tid + 256 * k;
    int uy = u >> 5, ux = u & 31;
    int bi = (ty0 >> 1) + uy;   // r1 rows 2bi, 2bi+1
    int bj = (tx0 >> 1) + ux;   // r1 cols 2bj, 2bj+1
    int c0 = 4 * bj;
    int cl = max(c0 - 1, 0), cr = min(c0 + 4, n - 1);
    float a[6][6];
#pragma unroll
    for (int rr = 0; rr < 6; ++rr) {
      int R = min(max(4 * bi - 1 + rr, 0), n - 1);
      const float* row = v + (size_t)R * n;
      float4 m = *reinterpret_cast<const float4*>(row + c0);
      a[rr][0] = row[cl];
      a[rr][1] = m.x; a[rr][2] = m.y; a[rr][3] = m.z; a[rr][4] = m.w;
      a[rr][5] = row[cr];
    }
#pragma unroll
    for (int oi = 0; oi < 2; ++oi) {
      float2 o;
#pragma unroll
      for (int oj = 0; oj < 2; ++oj) {
        float s[2][2];
#pragma unroll
        for (int p = 0; p < 2; ++p)
#pragma unroll
          for (int q = 0; q < 2; ++q) {
            int P = 2 * oi + p, Q = 2 * oj + q;
            s[p][q] = CW * a[P][Q + 1] - CW * a[P + 2][Q + 1]
                    + CW * a[P + 1][Q] + a[P + 1][Q + 1] - CW * a[P + 1][Q + 2];
          }
        float val = 0.25f * (((s[0][0] + s[1][0]) + s[0][1]) + s[1][1]);
        (oj ? o.y : o.x) = val;
        r1s[2 * uy + oi][2 * ux + oj] = val;
      }
      *reinterpret_cast<float2*>(r1 + (size_t)(2 * bi + oi) * h + 2 * bj) = o;
    }
  }
  __syncthreads();

  // Phase B: r2 32x32 (4/thread). Order: ((ee + oe) + eo) + oo.
#pragma unroll
  for (int k = 0; k < 4; ++k) {
    int idx = tid + 256 * k;
    int I = idx >> 5, J = idx & 31;
    float val = 0.25f * (((r1s[2 * I][2 * J] + r1s[2 * I + 1][2 * J])
                          + r1s[2 * I][2 * J + 1]) + r1s[2 * I + 1][2 * J + 1]);
    r2s[I][J] = val;
    r2[(size_t)(32 * by + I) * 1024 + 32 * bx + J] = val;
  }
  __syncthreads();

  // Phase C: r3 16x16 (1/thread for tid<256).
  {
    int I = tid >> 4, J = tid & 15;
    float val = 0.25f * (((r2s[2 * I][2 * J] + r2s[2 * I + 1][2 * J])
                          + r2s[2 * I][2 * J + 1]) + r2s[2 * I + 1][2 * J + 1]);
    r3s[I][J] = val;
    r3[(size_t)(16 * by + I) * 512 + 16 * bx + J] = val;
  }
  __syncthreads();

  // Phase D: r4 8x8 (tid<64).
  if (tid < 64) {
    int I = tid >> 3, J = tid & 7;
    float val = 0.25f * (((r3s[2 * I][2 * J] + r3s[2 * I + 1][2 * J])
                          + r3s[2 * I][2 * J + 1]) + r3s[2 * I + 1][2 * J + 1]);
    r4s[I][J] = val;
    r4[(size_t)(8 * by + I) * 256 + 8 * bx + J] = val;
  }
  __syncthreads();

  // Phase E: r5 4x4 (tid<16).
  if (tid < 16) {
    int I = tid >> 2, J = tid & 3;
    float val = 0.25f * (((r4s[2 * I][2 * J] + r4s[2 * I + 1][2 * J])
                          + r4s[2 * I][2 * J + 1]) + r4s[2 * I + 1][2 * J + 1]);
    r5[(size_t)(4 * by + I) * 128 + 4 * bx + J] = val;
  }
}

// ---------------------------------------------------------------------------
// k_coarse_ext: 16 blocks x 1024 thr. Each block redundantly computes the
// r5->r9 -> E9..E6 chain in LDS, then its 10 needed E5 rows, then writes
// E4 rows [16*bid, 16*bid+16) = up(E5, r4).
__global__ __launch_bounds__(1024, 1) void k_coarse_ext(
    const float* __restrict__ r5, const float* __restrict__ r4,
    float* __restrict__ E4) {
  __shared__ float r5s[128 * 128];
  __shared__ float r6s[64 * 64];
  __shared__ float r7s[32 * 32];
  __shared__ float r8s[16 * 16];
  __shared__ float r9s[8 * 8];
  __shared__ float E8s[16 * 16];
  __shared__ float E7s[32 * 32];
  __shared__ float E6s[64 * 64];
  __shared__ float e5r[10][128];  // E5 rows 8*bid-1 .. 8*bid+8
  int tid = threadIdx.x;
  int bid = blockIdx.x;

  auto up_lds = [&](const float* Ep, const float* rr, int i, int c, int nn) {
    int ss = nn >> 1;
    float Pc = Ep[(i >> 1) * ss + (c >> 1)];
    float Pu = (i > 0)      ? Ep[((i - 1) >> 1) * ss + (c >> 1)] : 0.0f;
    float Pd = (i < nn - 1) ? Ep[((i + 1) >> 1) * ss + (c >> 1)] : 0.0f;
    float Pl = (c > 0)      ? Ep[(i >> 1) * ss + ((c - 1) >> 1)] : 0.0f;
    float Pr = (c < nn - 1) ? Ep[(i >> 1) * ss + ((c + 1) >> 1)] : 0.0f;
    return up_val(Pc, Pu, Pd, Pl, Pr, rr[i * nn + c]);
  };

  for (int idx = tid; idx < 4096; idx += 1024)
    reinterpret_cast<float4*>(r5s)[idx] = reinterpret_cast<const float4*>(r5)[idx];
  __syncthreads();
  for (int idx = tid; idx < 64 * 64; idx += 1024) {
    int I = idx >> 6, J = idx & 63;
    float a = r5s[(2 * I) * 128 + 2 * J],     b = r5s[(2 * I + 1) * 128 + 2 * J];
    float c = r5s[(2 * I) * 128 + 2 * J + 1], d = r5s[(2 * I + 1) * 128 + 2 * J + 1];
    r6s[idx] = 0.25f * (((a + b) + c) + d);
  }
  __syncthreads();
  if (tid < 32 * 32) {
    int I = tid >> 5, J = tid & 31;
    float a = r6s[(2 * I) * 64 + 2 * J],     b = r6s[(2 * I + 1) * 64 + 2 * J];
    float c = r6s[(2 * I) * 64 + 2 * J + 1], d = r6s[(2 * I + 1) * 64 + 2 * J + 1];
    r7s[tid] = 0.25f * (((a + b) + c) + d);
  }
  __syncthreads();
  if (tid < 16 * 16) {
    int I = tid >> 4, J = tid & 15;
    float a = r7s[(2 * I) * 32 + 2 * J],     b = r7s[(2 * I + 1) * 32 + 2 * J];
    float c = r7s[(2 * I) * 32 + 2 * J + 1], d = r7s[(2 * I + 1) * 32 + 2 * J + 1];
    r8s[tid] = 0.25f * (((a + b) + c) + d);
  }
  __syncthreads();
  if (tid < 8 * 8) {
    int I = tid >> 3, J = tid & 7;
    float a = r8s[(2 * I) * 16 + 2 * J],     b = r8s[(2 * I + 1) * 16 + 2 * J];
    float c = r8s[(2 * I) * 16 + 2 * J + 1], d = r8s[(2 * I + 1) * 16 + 2 * J + 1];
    r9s[tid] = 0.25f * (((a + b) + c) + d);
  }
  __syncthreads();
  if (tid < 16 * 16)
    E8s[tid] = up_lds(r9s, r8s, tid >> 4, tid & 15, 16);
  __syncthreads();
  if (tid < 32 * 32)
    E7s[tid] = up_lds(E8s, r7s, tid >> 5, tid & 31, 32);
  __syncthreads();
  for (int idx = tid; idx < 64 * 64; idx += 1024)
    E6s[idx] = up_lds(E7s, r6s, idx >> 6, idx & 63, 64);
  __syncthreads();
  // E5 rows 8*bid-1 .. 8*bid+8 (clamped slots at the ends are never read).
  for (int idx = tid; idx < 10 * 128; idx += 1024) {
    int t = idx >> 7, c = idx & 127;
    int i = min(max(8 * bid - 1 + t, 0), 127);
    e5r[t][c] = up_lds(E6s, r5s, i, c, 128);
  }
  __syncthreads();
  // E4 rows 16*bid .. 16*bid+15 (n=256). slot = (row>>1) - 8*bid + 1.
  for (int idx = tid; idx < 16 * 256; idx += 1024) {
    int gi = 16 * bid + (idx >> 8);
    int gc = idx & 255;
    float Pc = e5r[(gi >> 1) - 8 * bid + 1][gc >> 1];
    float Pu = (gi > 0)   ? e5r[((gi - 1) >> 1) - 8 * bid + 1][gc >> 1] : 0.0f;
    float Pd = (gi < 255) ? e5r[((gi + 1) >> 1) - 8 * bid + 1][gc >> 1] : 0.0f;
    float Pl = (gc > 0)   ? e5r[(gi >> 1) - 8 * bid + 1][(gc - 1) >> 1] : 0.0f;
    float Pr = (gc < 255) ? e5r[(gi >> 1) - 8 * bid + 1][(gc + 1) >> 1] : 0.0f;
    E4[(size_t)gi * 256 + gc] = up_val(Pc, Pu, Pd, Pl, Pr, r4[(size_t)gi * 256 + gc]);
  }
}

// ---------------------------------------------------------------------------
// k_up_e3e2: block computes E3 region (34x34, zero OOB) in LDS from E4+r3,
// then its 64x64 E2 tile = up(E3, r2). E3 never goes to global.
__global__ __launch_bounds__(256) void k_up_e3e2(
    const float* __restrict__ E4, const float* __restrict__ r3,
    const float* __restrict__ r2, float* __restrict__ E2) {
  __shared__ float e3s[34][35];
  int tid = threadIdx.x;
  int bx = blockIdx.x, by = blockIdx.y;
  int br0 = 32 * by - 1, bc0 = 32 * bx - 1;  // e3s[0][0] = E3(br0, bc0)

  for (int idx = tid; idx < 34 * 34; idx += 256) {
    int er = idx / 34, ec = idx % 34;
    int gr = br0 + er, gc = bc0 + ec;
    float val = 0.0f;
    if (gr >= 0 && gr < 512 && gc >= 0 && gc < 512) {
      float Pc = E4[(size_t)(gr >> 1) * 256 + (gc >> 1)];
      float Pu = (gr > 0)   ? E4[(size_t)((gr - 1) >> 1) * 256 + (gc >> 1)] : 0.0f;
      float Pd = (gr < 511) ? E4[(size_t)((gr + 1) >> 1) * 256 + (gc >> 1)] : 0.0f;
      float Pl = (gc > 0)   ? E4[(size_t)(gr >> 1) * 256 + ((gc - 1) >> 1)] : 0.0f;
      float Pr = (gc < 511) ? E4[(size_t)(gr >> 1) * 256 + ((gc + 1) >> 1)] : 0.0f;
      val = up_val(Pc, Pu, Pd, Pl, Pr, r3[(size_t)gr * 512 + gc]);
    }
    e3s[er][ec] = val;
  }
  __syncthreads();

  // E2 tile 64x64: 1024 float4-units, 4/thread.
#pragma unroll
  for (int k = 0; k < 4; ++k) {
    int u = tid + 256 * k;
    int rr = u >> 4, f = u & 15;
    int gR = 64 * by + rr;
    int gC = 64 * bx + 4 * f;
    int rc = (gR >> 1) - br0;
    int ru = ((gR - 1) >> 1) - br0;   // valid when gR>0
    int rd = ((gR + 1) >> 1) - br0;   // valid when gR<1023
    float4 rv = *reinterpret_cast<const float4*>(r2 + (size_t)gR * 1024 + gC);
    float4 o;
#pragma unroll
    for (int q = 0; q < 4; ++q) {
      int c = gC + q;
      int lc = (c >> 1) - bc0;
      float Pc = e3s[rc][lc];
      float Pu = (gR > 0)    ? e3s[ru][lc] : 0.0f;
      float Pd = (gR < 1023) ? e3s[rd][lc] : 0.0f;
      float Pl = (c > 0)     ? e3s[rc][((c - 1) >> 1) - bc0] : 0.0f;
      float Pr = (c < 1023)  ? e3s[rc][((c + 1) >> 1) - bc0] : 0.0f;
      (&o.x)[q] = up_val(Pc, Pu, Pd, Pl, Pr, (&rv.x)[q]);
    }
    *reinterpret_cast<float4*>(E2 + (size_t)gR * 1024 + gC) = o;
  }
}

// ---------------------------------------------------------------------------
// k_up (n=2048 only now): E1 = up(E2, r1). Verbatim R2.
__global__ __launch_bounds__(256) void k_up(
    const float* __restrict__ Ep, const float* __restrict__ r,
    float* __restrict__ Eo, int n) {
  int s = n >> 1;
  int j = blockIdx.x * blockDim.x + threadIdx.x;
  int i = blockIdx.y * blockDim.y + threadIdx.y;
  if (i >= s || j >= (n >> 2)) return;
  const float* ec = Ep + (size_t)i * s + 2 * j;
  float epc0 = ec[0], epc1 = ec[1];
  float epl = (j > 0) ? ec[-1] : 0.0f;
  float epr = (2 * j + 2 < s) ? ec[2] : 0.0f;
  float epu0 = 0.0f, epu1 = 0.0f, epd0 = 0.0f, epd1 = 0.0f;
  if (i > 0)     { epu0 = ec[-s]; epu1 = ec[-s + 1]; }
  if (i < s - 1) { epd0 = ec[s];  epd1 = ec[s + 1]; }
  {
    float4 rv = *reinterpret_cast<const float4*>(r + (size_t)(2 * i) * n + 4 * j);
    float4 o;
    o.x = up_val(epc0, epu0, epc0, epl,  epc0, rv.x);
    o.y = up_val(epc0, epu0, epc0, epc0, epc1, rv.y);
    o.z = up_val(epc1, epu1, epc1, epc0, epc1, rv.z);
    o.w = up_val(epc1, epu1, epc1, epc1, epr,  rv.w);
    *reinterpret_cast<float4*>(Eo + (size_t)(2 * i) * n + 4 * j) = o;
  }
  {
    float4 rv = *reinterpret_cast<const float4*>(r + (size_t)(2 * i + 1) * n + 4 * j);
    float4 o;
    o.x = up_val(epc0, epc0, epd0, epl,  epc0, rv.x);
    o.y = up_val(epc0, epc0, epd0, epc0, epc1, rv.y);
    o.z = up_val(epc1, epc1, epd1, epc0, epc1, rv.z);
    o.w = up_val(epc1, epc1, epd1, epc1, epr,  rv.w);
    *reinterpret_cast<float4*>(Eo + (size_t)(2 * i + 1) * n + 4 * j) = o;
  }
}

// ---------------------------------------------------------------------------
// out = w - smooth(bc(w)), w = v - prolong(E1).  (verbatim R2)
__global__ __launch_bounds__(256) void k_final(
    const float* __restrict__ v, const float* __restrict__ E1,
    float* __restrict__ out) {
  const int n = 4096, h = 2048;
  int J = blockIdx.x * blockDim.x + threadIdx.x;
  int i = blockIdx.y * blockDim.y + threadIdx.y;
  int c0 = 4 * J;
  int cl = max(c0 - 1, 0), cr = min(c0 + 4, n - 1);
  int ecl = cl >> 1, ecr = cr >> 1;

  float e[3][4];
  int ers0 = max(2 * i - 1, 0) >> 1;
  int ers2 = min(2 * i + 2, n - 1) >> 1;
  const int ers[3] = {ers0, i, ers2};
#pragma unroll
  for (int t = 0; t < 3; ++t) {
    const float* erow = E1 + (size_t)ers[t] * h;
    e[t][0] = erow[ecl];
    e[t][1] = erow[2 * J];
    e[t][2] = erow[2 * J + 1];
    e[t][3] = erow[ecr];
  }

  float w[4][6];
  const int tmap[4] = {0, 1, 1, 2};
#pragma unroll
  for (int rr = 0; rr < 4; ++rr) {
    int R = min(max(2 * i - 1 + rr, 0), n - 1);
    int t = tmap[rr];
    const float* vrow = v + (size_t)R * n;
    float4 m = *reinterpret_cast<const float4*>(vrow + c0);
    w[rr][0] = vrow[cl] - e[t][0];
    w[rr][1] = m.x - e[t][1];
    w[rr][2] = m.y - e[t][1];
    w[rr][3] = m.z - e[t][2];
    w[rr][4] = m.w - e[t][2];
    w[rr][5] = vrow[cr] - e[t][3];
  }
#pragma unroll
  for (int a = 0; a < 2; ++a) {
    float4 o;
#pragma unroll
    for (int qq = 0; qq < 4; ++qq) {
      float ce = w[a + 1][qq + 1];
      float sm = CW * w[a][qq + 1] - CW * w[a + 2][qq + 1]
               + CW * w[a + 1][qq] + ce - CW * w[a + 1][qq + 2];
      (&o.x)[qq] = ce - sm;
    }
    *reinterpret_cast<float4*>(out + (size_t)(2 * i + a) * n + c0) = o;
  }
}

// ---------------------------------------------------------------------------
extern "C" void kernel_launch(void* const* d_in, const int* in_sizes, int n_in,
                              void* d_out, int out_size, void* d_ws, size_t ws_size,
                              hipStream_t stream) {
  (void)in_sizes; (void)n_in; (void)out_size;
  float* u = (float*)d_in[0];
  float* out = (float*)d_out;
  char* ws = (char*)d_ws;

  size_t off = 0;
  auto alloc = [&](size_t elems) {
    float* p = (float*)(ws + off);
    off += (elems * sizeof(float) + 255) & ~(size_t)255;
    return p;
  };
  float* r1 = alloc(2048 * 2048);
  float* r2 = alloc(1024 * 1024);
  float* r3 = alloc(512 * 512);
  float* r4 = alloc(256 * 256);
  float* r5 = alloc(128 * 128);
  float* E4 = alloc(256 * 256);
  float* E2 = alloc(1024 * 1024);
  float* E1 = alloc(2048 * 2048);
  size_t pool = off;
  const size_t VB = (size_t)4096 * 4096 * sizeof(float);
  bool big = ws_size >= pool + VB;
  float* vws = (float*)(ws + pool);

  dim3 b(64, 4);
  auto iterate = [&](const float* vin, float* vout) {
    k_sr_chain<<<dim3(32, 32), 256, 0, stream>>>(vin, r1, r2, r3, r4, r5);
    k_coarse_ext<<<16, 1024, 0, stream>>>(r5, r4, E4);
    k_up_e3e2<<<dim3(16, 16), 256, 0, stream>>>(E4, r3, r2, E2);
    k_up<<<dim3(8, 256), b, 0, stream>>>(E2, r1, E1, 2048);
    k_final<<<dim3(16, 512), b, 0, stream>>>(vin, E1, vout);
  };

  if (big) {
    iterate(u, vws);
    iterate(vws, out);
    iterate(out, vws);
    iterate(vws, out);
  } else {
    iterate(u, out);
    iterate(out, u);
    iterate(u, out);
    iterate(out, u);
    hipMemcpyAsync(out, u, VB, hipMemcpyDeviceToDevice, stream);
  }
}